// Round 4
// baseline (226.000 us; speedup 1.0000x reference)
//
#include <hip/hip_runtime.h>

#define B_    32
#define L_    4096
#define DIN   150
#define DST   75
#define HID   75
#define INF30 1e30f

// ---------------- ws layout (floats) ----------------
// sp[B_*HID]  : state @ W0[:75] + b0      (2400 floats)
// m[B_]       : row max of s1             (32)
// inv[B_]     : 1/sum(exp(s1-m))          (32)

__global__ void k_zero(float* __restrict__ p, int n) {
    int i = blockIdx.x * 256 + threadIdx.x;
    if (i < n) p[i] = 0.f;
}

// sp[b][h] = b0[h] + sum_k state[b][k] * W0[k][h]
__global__ __launch_bounds__(128) void k_statepre(
    const float* __restrict__ state, const float* __restrict__ W0,
    const float* __restrict__ b0, float* __restrict__ sp) {
    int b = blockIdx.x;
    int h = threadIdx.x;
    if (h < HID) {
        float acc = b0[h];
        #pragma unroll 5
        for (int k = 0; k < DST; ++k)
            acc = fmaf(state[b * DST + k], W0[k * HID + h], acc);
        sp[b * HID + h] = acc;
    }
}

// One 64-thread block (1 wave) = 64 rows. Inputs staged in LDS in 3 chunks
// of 50 cols (pad 51 -> stride%32=19, <=2 lanes/bank = free). Weights are
// wave-uniform -> SGPR loads; inner loop is v_fmac(vacc, sW, vx).
#define ROWS 64
#define CW   50
#define CPAD 51
__global__ __launch_bounds__(64) void k_score(
    const float* __restrict__ in, const unsigned char* __restrict__ maskB,
    const float* __restrict__ W0, const float* __restrict__ W1,
    const float* __restrict__ b1, const float* __restrict__ sp,
    float* __restrict__ s1out) {
    __shared__ float xs[ROWS * CPAD];
    int blk = blockIdx.x;               // 2048 blocks
    int b   = blk >> 6;                 // 64 blocks per batch
    int l0  = (blk & 63) * ROWS;
    int tid = threadIdx.x;

    const float* src = in + (size_t)(b * L_ + l0) * DIN;

    float pre[HID];
    #pragma unroll
    for (int h = 0; h < HID; ++h) pre[h] = sp[b * HID + h];

    const float* w0i = W0 + DST * HID;  // input-part rows of W0

    for (int c = 0; c < 3; ++c) {
        __syncthreads();                 // previous chunk fully consumed
        for (int i = tid; i < ROWS * CW; i += 64) {
            int r = i / CW;
            int d = i - r * CW;
            xs[r * CPAD + d] = src[r * DIN + c * CW + d];
        }
        __syncthreads();
        #pragma unroll 2
        for (int d = 0; d < CW; ++d) {
            float x = xs[tid * CPAD + d];
            const float* wr = w0i + (c * CW + d) * HID;  // wave-uniform
            #pragma unroll
            for (int h = 0; h < HID; ++h) pre[h] = fmaf(x, wr[h], pre[h]);
        }
    }

    float s = b1[0];
    #pragma unroll
    for (int h = 0; h < HID; ++h) {
        float p  = pre[h];
        float e  = __expf(-2.f * fabsf(p));
        float th = (1.f - e) / (1.f + e);      // tanh(|p|)
        s = fmaf(copysignf(th, p), W1[h], s);
    }

    // Mask dtype autodetect: values are 0/1 only. If int32, bytes at
    // index 4i+1 are ALWAYS 0; if 1-byte bool they're random 0/1
    // (P[all 64 zero] = 2^-64). Wave-uniform vote -> no divergence.
    unsigned char probe = maskB[tid * 4 + 1];
    bool isI32 = __all(probe == 0);
    int l = l0 + tid;
    bool mv;
    if (isI32) mv = ((const int*)maskB)[b * L_ + l] != 0;
    else       mv = maskB[b * L_ + l] != 0;
    s1out[b * L_ + l] = s - (mv ? 0.f : INF30);
}

// Per-b max + sum(exp) over L
__global__ __launch_bounds__(256) void k_stats(
    const float* __restrict__ s1, float* __restrict__ mOut,
    float* __restrict__ invOut) {
    int b = blockIdx.x;
    int tid = threadIdx.x;
    const float* row = s1 + b * L_;

    float m = -INFINITY;
    for (int i = tid; i < L_; i += 256) m = fmaxf(m, row[i]);
    #pragma unroll
    for (int off = 32; off; off >>= 1) m = fmaxf(m, __shfl_down(m, off, 64));
    __shared__ float red[4];
    if ((tid & 63) == 0) red[tid >> 6] = m;
    __syncthreads();
    m = fmaxf(fmaxf(red[0], red[1]), fmaxf(red[2], red[3]));

    float sum = 0.f;
    for (int i = tid; i < L_; i += 256) sum += __expf(row[i] - m);
    #pragma unroll
    for (int off = 32; off; off >>= 1) sum += __shfl_down(sum, off, 64);
    __shared__ float red2[4];
    if ((tid & 63) == 0) red2[tid >> 6] = sum;
    __syncthreads();                      // cross-wave race fix
    if (tid == 0) {
        mOut[b]   = m;
        invOut[b] = 1.f / (red2[0] + red2[1] + red2[2] + red2[3]);
    }
}

// res[b][d] += sum_{l in chunk} softmax_w(l) * in[b][l][d]
#define CHUNK 128
__global__ __launch_bounds__(192) void k_weighted(
    const float* __restrict__ in, const float* __restrict__ s1,
    const float* __restrict__ mIn, const float* __restrict__ invIn,
    float* __restrict__ res) {
    int b   = blockIdx.y;
    int l0  = blockIdx.x * CHUNK;
    int tid = threadIdx.x;
    __shared__ float w[CHUNK];
    float m = mIn[b], inv = invIn[b];
    if (tid < CHUNK)
        w[tid] = __expf(s1[b * L_ + l0 + tid] - m) * inv;
    __syncthreads();
    if (tid < DIN) {
        float acc = 0.f;
        const float* p = in + (size_t)(b * L_ + l0) * DIN + tid;
        #pragma unroll 4
        for (int i = 0; i < CHUNK; ++i) acc = fmaf(w[i], p[i * DIN], acc);
        atomicAdd(&res[b * DIN + tid], acc);
    }
}

extern "C" void kernel_launch(void* const* d_in, const int* in_sizes, int n_in,
                              void* d_out, int out_size, void* d_ws, size_t ws_size,
                              hipStream_t stream) {
    const float*         inputs = (const float*)d_in[0];
    const float*         state  = (const float*)d_in[1];
    const unsigned char* cmask  = (const unsigned char*)d_in[2];
    const float*         W0     = (const float*)d_in[3];
    const float*         b0     = (const float*)d_in[4];
    const float*         W1     = (const float*)d_in[5];
    const float*         b1     = (const float*)d_in[6];

    float* res   = (float*)d_out;             // B*1*DIN = 4800
    float* s1    = (float*)d_out + B_ * DIN;  // B*L
    float* wsf   = (float*)d_ws;
    float* sp    = wsf;                       // 2400
    float* mBuf  = wsf + B_ * HID;            // 32
    float* invB  = wsf + B_ * HID + B_;       // 32

    k_zero<<<(B_ * DIN + 255) / 256, 256, 0, stream>>>(res, B_ * DIN);
    k_statepre<<<B_, 128, 0, stream>>>(state, W0, b0, sp);
    k_score<<<B_ * L_ / ROWS, ROWS, 0, stream>>>(inputs, cmask, W0, W1, b1, sp, s1);
    k_stats<<<B_, 256, 0, stream>>>(s1, mBuf, invB);
    dim3 gridW(L_ / CHUNK, B_);
    k_weighted<<<gridW, 192, 0, stream>>>(inputs, s1, mBuf, invB, res);
}